// Round 1
// baseline (588.124 us; speedup 1.0000x reference)
//
#include <hip/hip_runtime.h>
#include <math.h>

// Problem constants (match reference)
#define Bn   64
#define Cin0 8
#define Vn   4096
#define V2n  1024
#define KK   8
#define DEG  32
#define CL1n 32
#define CL2n 64
#define FC1N 512
#define FC1IN 16384
#define BN_EPS 1e-5f

struct Ptr8 { const float* p[8]; };

// ---------------- BatchNorm stats: per-channel sum / sumsq over (B,V) ----------------
__global__ void bn_stats_kernel(const float* __restrict__ x, float* __restrict__ stats) {
    int c = blockIdx.x;          // 8 channels
    int chunk = blockIdx.y;      // 16 chunks
    const int per = (Bn * Vn) / 16;  // 16384
    int base = chunk * per;
    float s = 0.f, s2 = 0.f;
    for (int i = threadIdx.x; i < per; i += 256) {
        int p = base + i;
        int b = p >> 12;         // /4096
        int v = p & 4095;
        float val = x[((size_t)b * Cin0 + c) * Vn + v];
        s += val; s2 += val * val;
    }
    __shared__ float r1[256], r2[256];
    r1[threadIdx.x] = s; r2[threadIdx.x] = s2;
    __syncthreads();
    for (int off = 128; off > 0; off >>= 1) {
        if (threadIdx.x < off) {
            r1[threadIdx.x] += r1[threadIdx.x + off];
            r2[threadIdx.x] += r2[threadIdx.x + off];
        }
        __syncthreads();
    }
    if (threadIdx.x == 0) {
        atomicAdd(&stats[c], r1[0]);
        atomicAdd(&stats[8 + c], r2[0]);
    }
}

// ------------- BN apply + transpose (B,C,V) -> x0[v*512 + c*64 + b] -------------
__global__ void bn_apply_t_kernel(const float* __restrict__ x, const float* __restrict__ stats,
                                  float* __restrict__ x0) {
    int c = blockIdx.y;
    int v0 = blockIdx.x * 64;
    const float invN = 1.0f / (float)(Bn * Vn);
    float mean = stats[c] * invN;
    float var  = stats[8 + c] * invN - mean * mean;
    float sc = rsqrtf(var + BN_EPS);
    __shared__ float tile[64][65];
    int tx = threadIdx.x & 63;
    int ty = threadIdx.x >> 6;
    #pragma unroll
    for (int i = 0; i < 16; i++) {
        int b = i * 4 + ty;
        tile[b][tx] = x[((size_t)b * Cin0 + c) * Vn + v0 + tx];
    }
    __syncthreads();
    #pragma unroll
    for (int i = 0; i < 16; i++) {
        int vl = i * 4 + ty;
        float val = (tile[tx][vl] - mean) * sc;   // tx plays the role of b here
        x0[(size_t)(v0 + vl) * 512 + c * 64 + tx] = val;
    }
}

// ------------- SpMM: y[v,f] = scale-form of sum_e vals*x[cols[e],f] -------------
// Fixed out-degree DEG=32; row v's edges at [v*32, v*32+32). prev!=null => y = 2*acc - prev
__global__ void spmm_kernel(const float* __restrict__ xin, const int* __restrict__ cols,
                            const float* __restrict__ vals, const float* __restrict__ prev,
                            float* __restrict__ y, int F) {
    int v = blockIdx.x;
    int f = blockIdx.y * 512 + threadIdx.x * 4;
    __shared__ int   cs[DEG];
    __shared__ float vs[DEG];
    if (threadIdx.x < DEG) {
        cs[threadIdx.x] = cols[v * DEG + threadIdx.x];
        vs[threadIdx.x] = vals[v * DEG + threadIdx.x];
    }
    __syncthreads();
    float4 acc = make_float4(0.f, 0.f, 0.f, 0.f);
    #pragma unroll 8
    for (int e = 0; e < DEG; e++) {
        const float4 xv = *(const float4*)(xin + (size_t)cs[e] * F + f);
        float w = vs[e];
        acc.x += w * xv.x; acc.y += w * xv.y; acc.z += w * xv.z; acc.w += w * xv.w;
    }
    float4 o;
    if (prev) {
        const float4 pv = *(const float4*)(prev + (size_t)v * F + f);
        o.x = 2.f * acc.x - pv.x; o.y = 2.f * acc.y - pv.y;
        o.z = 2.f * acc.z - pv.z; o.w = 2.f * acc.w - pv.w;
    } else {
        o = acc;
    }
    *(float4*)(y + (size_t)v * F + f) = o;
}

// ------------- Dense combine: out = relu(xk @ W^T + b), fused maxpool4 + transpose -------------
// MODE 0 (graph1): out[(vp*Cout + j)*64 + b]   (= x0 layout of next graph stage, Cout=32)
// MODE 1 (graph2): out[((j*256 + vp))*64 + b]  (= transposed FC input A[m][b], Cout=64)
template <int CIN, int MODE>
__global__ void gemm_pool_kernel(Ptr8 xs, const float* __restrict__ W,
                                 const float* __restrict__ bias, float* __restrict__ out) {
    const int IN = CIN * KK;       // 64 or 256
    const int F  = CIN * 64;       // 512 or 2048
    __shared__ float Ws[32 * IN];
    int j0blk = blockIdx.y * 32;
    for (int i = threadIdx.x; i < 32 * IN; i += 256)
        Ws[i] = W[(size_t)(j0blk + i / IN) * IN + (i % IN)];
    __syncthreads();
    int b  = threadIdx.x & 63;
    int jg = threadIdx.x >> 6;     // 4 groups of 8 j's
    int vp = blockIdx.x;
    float acc[4][8];
    #pragma unroll
    for (int vl = 0; vl < 4; vl++)
        #pragma unroll
        for (int jj = 0; jj < 8; jj++)
            acc[vl][jj] = bias[j0blk + jg * 8 + jj];
    for (int k = 0; k < KK; k++) {
        const float* __restrict__ xp = xs.p[k];
        for (int c = 0; c < CIN; c++) {
            float xv[4];
            #pragma unroll
            for (int vl = 0; vl < 4; vl++)
                xv[vl] = xp[(size_t)(vp * 4 + vl) * F + c * 64 + b];
            #pragma unroll
            for (int jj = 0; jj < 8; jj++) {
                float w = Ws[(jg * 8 + jj) * IN + c * KK + k];
                acc[0][jj] += xv[0] * w;
                acc[1][jj] += xv[1] * w;
                acc[2][jj] += xv[2] * w;
                acc[3][jj] += xv[3] * w;
            }
        }
    }
    #pragma unroll
    for (int jj = 0; jj < 8; jj++) {
        float m0 = fmaxf(fmaxf(acc[0][jj], acc[1][jj]), fmaxf(acc[2][jj], acc[3][jj]));
        m0 = fmaxf(m0, 0.0f);   // relu-then-maxpool == max(0, max)
        int j = j0blk + jg * 8 + jj;
        if (MODE == 0)
            out[((size_t)vp * 32 + j) * 64 + b] = m0;
        else
            out[((size_t)j * 256 + vp) * 64 + b] = m0;
    }
}

// ------------- FC1 partial: part[mc][n][b] = sum over 512-m chunk of A[m][b]*W[n][m] -------------
__global__ void fc1_partial_kernel(const float* __restrict__ A,     // [16384][64]
                                   const float* __restrict__ Wfc,   // [512][16384]
                                   float* __restrict__ part) {      // [32][512][64]
    int n0 = blockIdx.x * 32;
    int m0 = blockIdx.y * 512;
    __shared__ float ws[32 * 128];
    int b  = threadIdx.x & 63;
    int ng = threadIdx.x >> 6;
    float acc[8];
    #pragma unroll
    for (int jn = 0; jn < 8; jn++) acc[jn] = 0.f;
    for (int ci = 0; ci < 4; ci++) {
        __syncthreads();
        for (int i = threadIdx.x; i < 32 * 128; i += 256) {
            int r = i >> 7, cc = i & 127;
            ws[i] = Wfc[(size_t)(n0 + r) * FC1IN + m0 + ci * 128 + cc];
        }
        __syncthreads();
        for (int mm = 0; mm < 128; mm++) {
            float a = A[(size_t)(m0 + ci * 128 + mm) * 64 + b];
            #pragma unroll
            for (int jn = 0; jn < 8; jn++)
                acc[jn] += a * ws[(ng * 8 + jn) * 128 + mm];
        }
    }
    #pragma unroll
    for (int jn = 0; jn < 8; jn++)
        part[((size_t)blockIdx.y * FC1N + n0 + ng * 8 + jn) * 64 + b] = acc[jn];
}

// ------------- FC1 reduce + bias + sigmoid -> Afc[n*64 + b] -------------
__global__ void fc1_reduce_kernel(const float* __restrict__ part, const float* __restrict__ bias,
                                  float* __restrict__ outA) {
    int idx = blockIdx.x * 256 + threadIdx.x;   // 32768 = 512*64
    int n = idx >> 6;
    float s = bias[n];
    for (int mc = 0; mc < 32; mc++) s += part[(size_t)mc * 32768 + idx];
    outA[idx] = 1.0f / (1.0f + expf(-s));
}

// ------------- FC2 -------------
__global__ void fc2_kernel(const float* __restrict__ Afc, const float* __restrict__ W,
                           const float* __restrict__ bias, float* __restrict__ out) {
    int t = threadIdx.x;        // 128 = 64 b * 2 o
    int b = t >> 1, o = t & 1;
    float s = bias[o];
    for (int n = 0; n < 512; n++)
        s += Afc[n * 64 + b] * W[o * 512 + n];
    out[b * 2 + o] = s;
}

extern "C" void kernel_launch(void* const* d_in, const int* in_sizes, int n_in,
                              void* d_out, int out_size, void* d_ws, size_t ws_size,
                              hipStream_t stream) {
    const float* x     = (const float*)d_in[0];
    const int*   cols1 = (const int*)  d_in[2];
    const float* vals1 = (const float*)d_in[3];
    const int*   cols2 = (const int*)  d_in[5];
    const float* vals2 = (const float*)d_in[6];
    const float* w1    = (const float*)d_in[7];
    const float* b1    = (const float*)d_in[8];
    const float* w2    = (const float*)d_in[9];
    const float* b2    = (const float*)d_in[10];
    const float* fc1w  = (const float*)d_in[11];
    const float* fc1b  = (const float*)d_in[12];
    const float* fc2w  = (const float*)d_in[13];
    const float* fc2b  = (const float*)d_in[14];

    float* ws = (float*)d_ws;
    const size_t SLOT = (size_t)Vn * 512;   // 2,097,152 floats (== V2*2048 too)
    float* stats = ws;                      // 16 floats
    float* xs    = ws + 64;                 // 8 slots
    float* x02   = xs + 8 * SLOT;           // graph2 x0 (V2 x 2048)
    float* h2pT  = x02 + SLOT;              // [16384][64] transposed FC input
    float* fc1p  = h2pT + (size_t)FC1IN * 64;   // [32][512][64] partials
    float* fc1o  = fc1p + (size_t)32 * FC1N * 64;
    // total ~21.0M floats = 84 MB of d_ws

    hipMemsetAsync(stats, 0, 16 * sizeof(float), stream);
    bn_stats_kernel<<<dim3(8, 16), 256, 0, stream>>>(x, stats);
    bn_apply_t_kernel<<<dim3(64, 8), 256, 0, stream>>>(x, stats, xs);

    // ---- graph conv 1: Chebyshev recursion, F=512 ----
    for (int k = 1; k < 8; k++)
        spmm_kernel<<<dim3(4096, 1), 128, 0, stream>>>(
            xs + (size_t)(k - 1) * SLOT, cols1, vals1,
            (k >= 2) ? xs + (size_t)(k - 2) * SLOT : nullptr,
            xs + (size_t)k * SLOT, 512);
    Ptr8 p1;
    for (int k = 0; k < 8; k++) p1.p[k] = xs + (size_t)k * SLOT;
    gemm_pool_kernel<8, 0><<<dim3(1024, 1), 256, 0, stream>>>(p1, w1, b1, x02);

    // ---- graph conv 2: F=2048, reuse xs slots (graph1 data dead now) ----
    Ptr8 p2;
    p2.p[0] = x02;
    for (int k = 1; k < 8; k++) p2.p[k] = xs + (size_t)(k - 1) * SLOT;
    for (int k = 1; k < 8; k++)
        spmm_kernel<<<dim3(1024, 4), 128, 0, stream>>>(
            p2.p[k - 1], cols2, vals2,
            (k >= 2) ? p2.p[k - 2] : nullptr,
            (float*)p2.p[k], 2048);
    gemm_pool_kernel<32, 1><<<dim3(256, 2), 256, 0, stream>>>(p2, w2, b2, h2pT);

    // ---- FC head ----
    fc1_partial_kernel<<<dim3(16, 32), 256, 0, stream>>>(h2pT, fc1w, fc1p);
    fc1_reduce_kernel<<<dim3(128), 256, 0, stream>>>(fc1p, fc1b, fc1o);
    fc2_kernel<<<dim3(1), 128, 0, stream>>>(fc1o, fc2w, fc2b, (float*)d_out);
}